// Round 4
// baseline (46.508 us; speedup 1.0000x reference)
//
#include <hip/hip_runtime.h>
#include <math.h>

#define S_LEN 520
#define E_DIM 6
#define H_N   3
#define NPAIR (H_N * S_LEN)       // 1560
#define K1_TPB 512
#define K1_BLKS 4                 // ceil(1560 / 512)
#define K2_TPB 256

typedef float f32x2 __attribute__((ext_vector_type(2)));

__device__ __forceinline__ float fast_exp2(float v) {
#if __has_builtin(__builtin_amdgcn_exp2f)
    return __builtin_amdgcn_exp2f(v);
#else
    return exp2f(v);
#endif
}

__device__ __forceinline__ f32x2 pk_fma(f32x2 a, f32x2 b, f32x2 c) {
    f32x2 d;
    asm("v_pk_fma_f32 %0, %1, %2, %3" : "=v"(d) : "v"(a), "v"(b), "v"(c));
    return d;
}
__device__ __forceinline__ f32x2 pk_add(f32x2 a, f32x2 b) {
    f32x2 d;
    asm("v_pk_add_f32 %0, %1, %2" : "=v"(d) : "v"(a), "v"(b));
    return d;
}

// ws layout:
//   wls   : B * NPAIR floats            @ 0
//   stats : B float2 {xmax, xmin}       @ B*NPAIR*4
//   csh   : 4 floats (3 used, *LOG2E)   @ B*NPAIR*4 + B*8

// ---------------------------------------------------------------------------
// K0: per-row max/min (one wave per row) + csh (block 0 only)
// ---------------------------------------------------------------------------
__global__ __launch_bounds__(64, 1) void k0_stats(
    const float* __restrict__ x,
    const float* __restrict__ Wq, const float* __restrict__ Wk,
    float2* __restrict__ stats, float* __restrict__ csh_out)
{
    const int b    = blockIdx.x;
    const int lane = threadIdx.x;

    float mx = -1e30f, mn = 1e30f;
    const float* xr = x + b * S_LEN;
    for (int i = lane; i < S_LEN; i += 64) {
        float v = xr[i];
        mx = fmaxf(mx, v);
        mn = fminf(mn, v);
    }
    for (int off = 32; off > 0; off >>= 1) {
        mx = fmaxf(mx, __shfl_down(mx, off));
        mn = fminf(mn, __shfl_down(mn, off));
    }
    if (lane == 0) stats[b] = make_float2(mx, mn);

    if (b == 0) {
        __shared__ float qk[2][E_DIM];
        if (lane < 2 * E_DIM) {
            const float* W = (lane < E_DIM) ? Wq : Wk;
            int e = (lane < E_DIM) ? lane : lane - E_DIM;
            float sum = 0.f;
            #pragma unroll
            for (int i = 0; i < E_DIM; ++i) sum += W[i * E_DIM + e];
            qk[lane / E_DIM][e] = sum;
        }
        __syncthreads();
        if (lane < H_N) {
            const float LOG2E = 1.4426950408889634f;
            csh_out[lane] = (qk[0][2*lane] * qk[1][2*lane]
                           + qk[0][2*lane+1] * qk[1][2*lane+1])
                          * 0.7071067811865476f * LOG2E;
        }
    }
}

// ---------------------------------------------------------------------------
// K1: one thread per (b,h,s) pair. 512 threads/block, 4 x-blocks per row.
//   w[b,h,s] = sum_t x_t e^{a x_t} / sum_t e^{a x_t},  a2 = csh[h]*x_s (log2-dom)
// ---------------------------------------------------------------------------
__global__ __launch_bounds__(K1_TPB, 8) void k1_pairs(
    const float* __restrict__ x,
    const float2* __restrict__ stats,
    const float* __restrict__ csh,
    float* __restrict__ wls)
{
    const int b   = blockIdx.y;
    const int tid = threadIdx.x;

    __shared__ __align__(16) float xs[S_LEN];

    // stage x row: 130 float4 (row byte offset 2080 is 16B aligned)
    if (tid < S_LEN / 4)
        ((float4*)xs)[tid] = ((const float4*)(x + b * S_LEN))[tid];

    // uniform scalars (issue before barrier; L2 broadcast)
    const float2 st = stats[b];

    const int p = blockIdx.x * K1_TPB + tid;
    const int h = (p >= 2 * S_LEN) ? 2 : (p >= S_LEN ? 1 : 0);
    const int s = p - h * S_LEN;
    const float c = csh[h];

    __syncthreads();
    if (p >= NPAIR) return;

    const float a2 = c * xs[s];
    const float m2 = (a2 >= 0.f) ? a2 * st.x : a2 * st.y;

    const f32x2 a2p  = {a2, a2};
    const f32x2 nm2p = {-m2, -m2};

    const float4* xs4 = (const float4*)xs;

    f32x2 den0 = {0.f, 0.f}, den1 = {0.f, 0.f}, den2 = {0.f, 0.f}, den3 = {0.f, 0.f};
    f32x2 num0 = {0.f, 0.f}, num1 = {0.f, 0.f}, num2 = {0.f, 0.f}, num3 = {0.f, 0.f};

    for (int it = 0; it < S_LEN / 8; ++it) {
        float4 xa = xs4[2 * it];
        float4 xb = xs4[2 * it + 1];
        f32x2 x0 = {xa.x, xa.y};
        f32x2 x1 = {xa.z, xa.w};
        f32x2 x2 = {xb.x, xb.y};
        f32x2 x3 = {xb.z, xb.w};

        f32x2 g0 = pk_fma(a2p, x0, nm2p);
        f32x2 g1 = pk_fma(a2p, x1, nm2p);
        f32x2 g2 = pk_fma(a2p, x2, nm2p);
        f32x2 g3 = pk_fma(a2p, x3, nm2p);

        f32x2 e0 = { fast_exp2(g0.x), fast_exp2(g0.y) };
        f32x2 e1 = { fast_exp2(g1.x), fast_exp2(g1.y) };
        f32x2 e2 = { fast_exp2(g2.x), fast_exp2(g2.y) };
        f32x2 e3 = { fast_exp2(g3.x), fast_exp2(g3.y) };

        den0 = pk_add(den0, e0);
        den1 = pk_add(den1, e1);
        den2 = pk_add(den2, e2);
        den3 = pk_add(den3, e3);

        num0 = pk_fma(e0, x0, num0);
        num1 = pk_fma(e1, x1, num1);
        num2 = pk_fma(e2, x2, num2);
        num3 = pk_fma(e3, x3, num3);
    }

    f32x2 denp = pk_add(pk_add(den0, den1), pk_add(den2, den3));
    f32x2 nump = pk_add(pk_add(num0, num1), pk_add(num2, num3));
    float den = denp.x + denp.y;
    float num = nump.x + nump.y;
    wls[(b * H_N + h) * S_LEN + s] = num / den;
}

// ---------------------------------------------------------------------------
// K2: per batch row — Wo-combine + LN1 + fc1 + relu + LN2 + fc2 + softmax(4)
// ---------------------------------------------------------------------------
__global__ __launch_bounds__(K2_TPB, 1) void k2_tail(
    const float* __restrict__ wls,
    const float* __restrict__ Wv, const float* __restrict__ Wo,
    const float* __restrict__ ln1_g, const float* __restrict__ ln1_b,
    const float* __restrict__ fc1_w, const float* __restrict__ fc1_b,
    const float* __restrict__ ln2_g, const float* __restrict__ ln2_b,
    const float* __restrict__ fc2_w, const float* __restrict__ fc2_b,
    float* __restrict__ out)
{
    const int b   = blockIdx.x;
    const int tid = threadIdx.x;

    __shared__ float Msh[H_N][E_DIM];
    __shared__ float wred[K2_TPB / 64][E_DIM];
    __shared__ float g1[E_DIM], b1[E_DIM];

    if (tid == 0) {
        float vv[E_DIM];
        #pragma unroll
        for (int e = 0; e < E_DIM; ++e) {
            float v = 0.f;
            #pragma unroll
            for (int i = 0; i < E_DIM; ++i) v += Wv[i * E_DIM + e];
            vv[e] = v;
        }
        for (int h = 0; h < H_N; ++h)
            #pragma unroll
            for (int e = 0; e < E_DIM; ++e)
                Msh[h][e] = vv[2*h] * Wo[(2*h) * E_DIM + e]
                          + vv[2*h+1] * Wo[(2*h+1) * E_DIM + e];
    }
    if (tid < E_DIM) { g1[tid] = ln1_g[tid]; b1[tid] = ln1_b[tid]; }
    __syncthreads();

    float yacc[E_DIM] = {0.f, 0.f, 0.f, 0.f, 0.f, 0.f};
    const float* wb = wls + b * NPAIR;
    for (int s = tid; s < S_LEN; s += K2_TPB) {
        float w0 = wb[s], w1 = wb[S_LEN + s], w2 = wb[2 * S_LEN + s];
        float o[E_DIM];
        float mean = 0.f;
        #pragma unroll
        for (int e = 0; e < E_DIM; ++e) {
            o[e] = w0 * Msh[0][e] + w1 * Msh[1][e] + w2 * Msh[2][e];
            mean += o[e];
        }
        mean *= (1.f / E_DIM);
        float var = 0.f;
        #pragma unroll
        for (int e = 0; e < E_DIM; ++e) { float d = o[e] - mean; var += d * d; }
        var *= (1.f / E_DIM);
        float r = rsqrtf(var + 1e-5f);
        float ln[E_DIM];
        #pragma unroll
        for (int e = 0; e < E_DIM; ++e)
            ln[e] = (o[e] - mean) * r * g1[e] + b1[e];

        const float* wrow = fc1_w + s * E_DIM;
        #pragma unroll
        for (int i = 0; i < E_DIM; ++i) {
            const float* wr = wrow + i * (S_LEN * E_DIM);
            float acc = yacc[i];
            #pragma unroll
            for (int e = 0; e < E_DIM; ++e) acc = fmaf(ln[e], wr[e], acc);
            yacc[i] = acc;
        }
    }

    #pragma unroll
    for (int i = 0; i < E_DIM; ++i)
        for (int off = 32; off > 0; off >>= 1)
            yacc[i] += __shfl_down(yacc[i], off);
    if ((tid & 63) == 0) {
        #pragma unroll
        for (int i = 0; i < E_DIM; ++i) wred[tid >> 6][i] = yacc[i];
    }
    __syncthreads();

    if (tid == 0) {
        const float LOG2E = 1.4426950408889634f;
        float y[E_DIM];
        float mean = 0.f;
        #pragma unroll
        for (int i = 0; i < E_DIM; ++i) {
            float t = wred[0][i];
            for (int w = 1; w < K2_TPB / 64; ++w) t += wred[w][i];
            y[i] = fmaxf(t + fc1_b[i], 0.f);
            mean += y[i];
        }
        mean *= (1.f / E_DIM);
        float var = 0.f;
        #pragma unroll
        for (int i = 0; i < E_DIM; ++i) { float d = y[i] - mean; var += d * d; }
        var *= (1.f / E_DIM);
        float r = rsqrtf(var + 1e-5f);
        float l2[E_DIM];
        #pragma unroll
        for (int i = 0; i < E_DIM; ++i)
            l2[i] = (y[i] - mean) * r * ln2_g[i] + ln2_b[i];

        float z[4];
        float zmax = -1e30f;
        #pragma unroll
        for (int k = 0; k < 4; ++k) {
            float acc = fc2_b[k];
            #pragma unroll
            for (int i = 0; i < E_DIM; ++i)
                acc = fmaf(l2[i], fc2_w[k * E_DIM + i], acc);
            z[k] = acc;
            zmax = fmaxf(zmax, acc);
        }
        float ez[4];
        float se = 0.f;
        #pragma unroll
        for (int k = 0; k < 4; ++k) {
            ez[k] = fast_exp2((z[k] - zmax) * LOG2E);
            se += ez[k];
        }
        float inv = 1.f / se;
        #pragma unroll
        for (int k = 0; k < 4; ++k) out[b * 4 + k] = ez[k] * inv;
    }
}

// ---------------------------------------------------------------------------
// Fallback: single fused kernel (used only if ws_size is too small)
// ---------------------------------------------------------------------------
#define TPB   320
#define NWAVE (TPB / 64)

__global__ __launch_bounds__(TPB, 1) void fused_tx_kernel(
    const float* __restrict__ x,
    const float* __restrict__ Wq, const float* __restrict__ Wk,
    const float* __restrict__ Wv, const float* __restrict__ Wo,
    const float* __restrict__ ln1_g, const float* __restrict__ ln1_b,
    const float* __restrict__ fc1_w, const float* __restrict__ fc1_b,
    const float* __restrict__ ln2_g, const float* __restrict__ ln2_b,
    const float* __restrict__ fc2_w, const float* __restrict__ fc2_b,
    float* __restrict__ out)
{
    const int b   = blockIdx.x;
    const int tid = threadIdx.x;

    __shared__ __align__(16) float xs[S_LEN];
    __shared__ float csh[H_N];
    __shared__ float Msh[H_N][E_DIM];
    __shared__ float wls[H_N][S_LEN];
    __shared__ float wred[NWAVE][2];
    __shared__ float xmax_s, xmin_s;
    __shared__ float ysum[E_DIM];

    for (int i = tid; i < S_LEN; i += TPB) xs[i] = x[b * S_LEN + i];
    if (tid < E_DIM) ysum[tid] = 0.f;

    if (tid == 0) {
        float qv[E_DIM], kv[E_DIM], vv[E_DIM];
        for (int e = 0; e < E_DIM; ++e) {
            float q = 0.f, k = 0.f, v = 0.f;
            for (int i = 0; i < E_DIM; ++i) {
                q += Wq[i * E_DIM + e];
                k += Wk[i * E_DIM + e];
                v += Wv[i * E_DIM + e];
            }
            qv[e] = q; kv[e] = k; vv[e] = v;
        }
        const float inv_sqrt_d = 0.7071067811865476f;
        for (int h = 0; h < H_N; ++h) {
            csh[h] = (qv[2*h] * kv[2*h] + qv[2*h+1] * kv[2*h+1]) * inv_sqrt_d;
            for (int e = 0; e < E_DIM; ++e)
                Msh[h][e] = vv[2*h] * Wo[(2*h) * E_DIM + e]
                          + vv[2*h+1] * Wo[(2*h+1) * E_DIM + e];
        }
    }
    __syncthreads();

    {
        float mx = -1e30f, mn = 1e30f;
        for (int i = tid; i < S_LEN; i += TPB) {
            float v = xs[i];
            mx = fmaxf(mx, v);
            mn = fminf(mn, v);
        }
        for (int off = 32; off > 0; off >>= 1) {
            mx = fmaxf(mx, __shfl_down(mx, off));
            mn = fminf(mn, __shfl_down(mn, off));
        }
        int wave = tid >> 6, lane = tid & 63;
        if (lane == 0) { wred[wave][0] = mx; wred[wave][1] = mn; }
        __syncthreads();
        if (tid == 0) {
            float a = wred[0][0], c = wred[0][1];
            for (int w = 1; w < NWAVE; ++w) {
                a = fmaxf(a, wred[w][0]);
                c = fminf(c, wred[w][1]);
            }
            xmax_s = a; xmin_s = c;
        }
        __syncthreads();
    }

    const float LOG2E = 1.4426950408889634f;
    const float xmax = xmax_s, xmin = xmin_s;
    const float4* xs4 = (const float4*)xs;

    for (int p = tid; p < NPAIR; p += TPB) {
        int h = p / S_LEN;
        int s = p - h * S_LEN;
        float a  = csh[h] * xs[s];
        float a2 = a * LOG2E;
        float m2 = (a >= 0.f ? a * xmax : a * xmin) * LOG2E;

        float den0 = 0.f, den1 = 0.f, den2 = 0.f, den3 = 0.f;
        float num0 = 0.f, num1 = 0.f, num2 = 0.f, num3 = 0.f;
        #pragma unroll 2
        for (int t4 = 0; t4 < S_LEN / 4; ++t4) {
            float4 xv = xs4[t4];
            float e0 = fast_exp2(fmaf(a2, xv.x, -m2));
            float e1 = fast_exp2(fmaf(a2, xv.y, -m2));
            float e2 = fast_exp2(fmaf(a2, xv.z, -m2));
            float e3 = fast_exp2(fmaf(a2, xv.w, -m2));
            den0 += e0; den1 += e1; den2 += e2; den3 += e3;
            num0 = fmaf(e0, xv.x, num0);
            num1 = fmaf(e1, xv.y, num1);
            num2 = fmaf(e2, xv.z, num2);
            num3 = fmaf(e3, xv.w, num3);
        }
        float den = (den0 + den1) + (den2 + den3);
        float num = (num0 + num1) + (num2 + num3);
        wls[h][s] = num / den;
    }
    __syncthreads();

    float yacc[E_DIM] = {0.f, 0.f, 0.f, 0.f, 0.f, 0.f};
    for (int s = tid; s < S_LEN; s += TPB) {
        float w0 = wls[0][s], w1 = wls[1][s], w2 = wls[2][s];
        float o[E_DIM];
        float mean = 0.f;
        #pragma unroll
        for (int e = 0; e < E_DIM; ++e) {
            o[e] = w0 * Msh[0][e] + w1 * Msh[1][e] + w2 * Msh[2][e];
            mean += o[e];
        }
        mean *= (1.f / E_DIM);
        float var = 0.f;
        #pragma unroll
        for (int e = 0; e < E_DIM; ++e) { float d = o[e] - mean; var += d * d; }
        var *= (1.f / E_DIM);
        float r = rsqrtf(var + 1e-5f);
        float ln[E_DIM];
        #pragma unroll
        for (int e = 0; e < E_DIM; ++e)
            ln[e] = (o[e] - mean) * r * ln1_g[e] + ln1_b[e];

        const float* wrow = fc1_w + s * E_DIM;
        #pragma unroll
        for (int i = 0; i < E_DIM; ++i) {
            const float* wr = wrow + i * (S_LEN * E_DIM);
            float acc = yacc[i];
            #pragma unroll
            for (int e = 0; e < E_DIM; ++e) acc = fmaf(ln[e], wr[e], acc);
            yacc[i] = acc;
        }
    }

    #pragma unroll
    for (int i = 0; i < E_DIM; ++i)
        for (int off = 32; off > 0; off >>= 1)
            yacc[i] += __shfl_down(yacc[i], off);
    if ((tid & 63) == 0) {
        #pragma unroll
        for (int i = 0; i < E_DIM; ++i) atomicAdd(&ysum[i], yacc[i]);
    }
    __syncthreads();

    if (tid == 0) {
        float y[E_DIM];
        float mean = 0.f;
        #pragma unroll
        for (int i = 0; i < E_DIM; ++i) {
            y[i] = fmaxf(ysum[i] + fc1_b[i], 0.f);
            mean += y[i];
        }
        mean *= (1.f / E_DIM);
        float var = 0.f;
        #pragma unroll
        for (int i = 0; i < E_DIM; ++i) { float d = y[i] - mean; var += d * d; }
        var *= (1.f / E_DIM);
        float r = rsqrtf(var + 1e-5f);
        float l2[E_DIM];
        #pragma unroll
        for (int i = 0; i < E_DIM; ++i)
            l2[i] = (y[i] - mean) * r * ln2_g[i] + ln2_b[i];

        float z[4];
        float zmax = -1e30f;
        #pragma unroll
        for (int k = 0; k < 4; ++k) {
            float acc = fc2_b[k];
            #pragma unroll
            for (int i = 0; i < E_DIM; ++i)
                acc = fmaf(l2[i], fc2_w[k * E_DIM + i], acc);
            z[k] = acc;
            zmax = fmaxf(zmax, acc);
        }
        float ez[4];
        float se = 0.f;
        #pragma unroll
        for (int k = 0; k < 4; ++k) {
            ez[k] = fast_exp2((z[k] - zmax) * LOG2E);
            se += ez[k];
        }
        float inv = 1.f / se;
        #pragma unroll
        for (int k = 0; k < 4; ++k) out[b * 4 + k] = ez[k] * inv;
    }
}

extern "C" void kernel_launch(void* const* d_in, const int* in_sizes, int n_in,
                              void* d_out, int out_size, void* d_ws, size_t ws_size,
                              hipStream_t stream) {
    const float* x     = (const float*)d_in[0];
    const float* Wq    = (const float*)d_in[1];
    const float* Wk    = (const float*)d_in[2];
    const float* Wv    = (const float*)d_in[3];
    const float* Wo    = (const float*)d_in[4];
    const float* ln1_g = (const float*)d_in[5];
    const float* ln1_b = (const float*)d_in[6];
    const float* fc1_w = (const float*)d_in[7];
    const float* fc1_b = (const float*)d_in[8];
    const float* ln2_g = (const float*)d_in[9];
    const float* ln2_b = (const float*)d_in[10];
    const float* fc2_w = (const float*)d_in[11];
    const float* fc2_b = (const float*)d_in[12];
    float* out = (float*)d_out;

    const int B = in_sizes[0] / S_LEN;   // 256
    const size_t wls_bytes   = (size_t)B * NPAIR * sizeof(float);
    const size_t stats_bytes = (size_t)B * sizeof(float2);
    const size_t need = wls_bytes + stats_bytes + 4 * sizeof(float);

    if (ws_size >= need) {
        float*  wls   = (float*)d_ws;
        float2* stats = (float2*)((char*)d_ws + wls_bytes);
        float*  csh   = (float*)((char*)d_ws + wls_bytes + stats_bytes);

        k0_stats<<<B, 64, 0, stream>>>(x, Wq, Wk, stats, csh);
        dim3 grid1(K1_BLKS, B);
        k1_pairs<<<grid1, K1_TPB, 0, stream>>>(x, stats, csh, wls);
        k2_tail<<<B, K2_TPB, 0, stream>>>(wls, Wv, Wo, ln1_g, ln1_b,
                                          fc1_w, fc1_b, ln2_g, ln2_b,
                                          fc2_w, fc2_b, out);
    } else {
        fused_tx_kernel<<<B, TPB, 0, stream>>>(
            x, Wq, Wk, Wv, Wo, ln1_g, ln1_b, fc1_w, fc1_b,
            ln2_g, ln2_b, fc2_w, fc2_b, out);
    }
}

// Round 5
// 43.270 us; speedup vs baseline: 1.0748x; 1.0748x over previous
//
#include <hip/hip_runtime.h>
#include <math.h>

#define S_LEN 520
#define E_DIM 6
#define H_N   3
#define NPAIR (H_N * S_LEN)       // 1560
#define K1_TPB 256
#define K1_BLKS 7                 // ceil(1560 / 256)
#define K2_TPB 256

typedef float f32x2 __attribute__((ext_vector_type(2)));

__device__ __forceinline__ float fast_exp2(float v) {
#if __has_builtin(__builtin_amdgcn_exp2f)
    return __builtin_amdgcn_exp2f(v);
#else
    return exp2f(v);
#endif
}

__device__ __forceinline__ f32x2 pk_fma(f32x2 a, f32x2 b, f32x2 c) {
    f32x2 d;
    asm("v_pk_fma_f32 %0, %1, %2, %3" : "=v"(d) : "v"(a), "v"(b), "v"(c));
    return d;
}
__device__ __forceinline__ f32x2 pk_add(f32x2 a, f32x2 b) {
    f32x2 d;
    asm("v_pk_add_f32 %0, %1, %2" : "=v"(d) : "v"(a), "v"(b));
    return d;
}

// ---------------------------------------------------------------------------
// K1: one thread per (b,h,s) pair. Barrier-free, LDS-free.
//   - per-wave: row max/min via coalesced loads + shfl_xor; csh from uniform
//     scalar loads (all redundant per wave, negligible).
//   - hot loop: x_t read with loop-uniform global index -> s_load into SGPRs,
//     consumed directly as SGPR operands by the packed VALU ops.
// ---------------------------------------------------------------------------
__global__ __launch_bounds__(K1_TPB) void k1_pairs(
    const float* __restrict__ x,
    const float* __restrict__ Wq, const float* __restrict__ Wk,
    float* __restrict__ wls)
{
    const int b   = blockIdx.y;
    const int tid = threadIdx.x;
    const float* __restrict__ xrow = x + b * S_LEN;

    // ---- per-wave row max/min (all threads participate; no barriers) ----
    float mx = -1e30f, mn = 1e30f;
    for (int i = (tid & 63); i < S_LEN; i += 64) {
        float v = xrow[i];
        mx = fmaxf(mx, v);
        mn = fminf(mn, v);
    }
    #pragma unroll
    for (int off = 32; off > 0; off >>= 1) {
        mx = fmaxf(mx, __shfl_xor(mx, off));
        mn = fminf(mn, __shfl_xor(mn, off));
    }

    // ---- per-wave csh (uniform scalar math, ~70 cy) ----
    float c0, c1, c2;
    {
        const float SC = 0.7071067811865476f * 1.4426950408889634f; // 1/sqrt(2)*log2(e)
        float cs[H_N];
        #pragma unroll
        for (int h = 0; h < H_N; ++h) {
            float q0 = 0.f, q1 = 0.f, k0 = 0.f, k1 = 0.f;
            #pragma unroll
            for (int i = 0; i < E_DIM; ++i) {
                q0 += Wq[i * E_DIM + 2*h];
                q1 += Wq[i * E_DIM + 2*h + 1];
                k0 += Wk[i * E_DIM + 2*h];
                k1 += Wk[i * E_DIM + 2*h + 1];
            }
            cs[h] = (q0 * k0 + q1 * k1) * SC;
        }
        c0 = cs[0]; c1 = cs[1]; c2 = cs[2];
    }

    const int p = blockIdx.x * K1_TPB + tid;
    if (p >= NPAIR) return;
    const int h = (p >= 2 * S_LEN) ? 2 : (p >= S_LEN ? 1 : 0);
    const int s = p - h * S_LEN;
    const float c = (h == 0) ? c0 : (h == 1 ? c1 : c2);

    const float a2 = c * xrow[s];                       // log2-domain scale
    const float m2 = (a2 >= 0.f) ? a2 * mx : a2 * mn;   // exact row max of a2*x_t

    const f32x2 a2p  = {a2, a2};
    const f32x2 nm2p = {-m2, -m2};

    f32x2 den0 = {0.f, 0.f}, den1 = {0.f, 0.f}, den2 = {0.f, 0.f}, den3 = {0.f, 0.f};
    f32x2 num0 = {0.f, 0.f}, num1 = {0.f, 0.f}, num2 = {0.f, 0.f}, num3 = {0.f, 0.f};

    for (int it = 0; it < S_LEN / 8; ++it) {
        const float* __restrict__ xp = xrow + it * 8;   // uniform address -> s_load
        f32x2 x0 = {xp[0], xp[1]};
        f32x2 x1 = {xp[2], xp[3]};
        f32x2 x2 = {xp[4], xp[5]};
        f32x2 x3 = {xp[6], xp[7]};

        f32x2 g0 = pk_fma(a2p, x0, nm2p);
        f32x2 g1 = pk_fma(a2p, x1, nm2p);
        f32x2 g2 = pk_fma(a2p, x2, nm2p);
        f32x2 g3 = pk_fma(a2p, x3, nm2p);

        f32x2 e0 = { fast_exp2(g0.x), fast_exp2(g0.y) };
        f32x2 e1 = { fast_exp2(g1.x), fast_exp2(g1.y) };
        f32x2 e2 = { fast_exp2(g2.x), fast_exp2(g2.y) };
        f32x2 e3 = { fast_exp2(g3.x), fast_exp2(g3.y) };

        den0 = pk_add(den0, e0);
        den1 = pk_add(den1, e1);
        den2 = pk_add(den2, e2);
        den3 = pk_add(den3, e3);

        num0 = pk_fma(e0, x0, num0);
        num1 = pk_fma(e1, x1, num1);
        num2 = pk_fma(e2, x2, num2);
        num3 = pk_fma(e3, x3, num3);
    }

    f32x2 denp = pk_add(pk_add(den0, den1), pk_add(den2, den3));
    f32x2 nump = pk_add(pk_add(num0, num1), pk_add(num2, num3));
    float den = denp.x + denp.y;
    float num = nump.x + nump.y;
    wls[(b * H_N + h) * S_LEN + s] = num / den;
}

// ---------------------------------------------------------------------------
// K2: per batch row — Wo-combine + LN1 + fc1 + relu + LN2 + fc2 + softmax(4)
// ---------------------------------------------------------------------------
__global__ __launch_bounds__(K2_TPB, 1) void k2_tail(
    const float* __restrict__ wls,
    const float* __restrict__ Wv, const float* __restrict__ Wo,
    const float* __restrict__ ln1_g, const float* __restrict__ ln1_b,
    const float* __restrict__ fc1_w, const float* __restrict__ fc1_b,
    const float* __restrict__ ln2_g, const float* __restrict__ ln2_b,
    const float* __restrict__ fc2_w, const float* __restrict__ fc2_b,
    float* __restrict__ out)
{
    const int b   = blockIdx.x;
    const int tid = threadIdx.x;

    __shared__ float Msh[H_N][E_DIM];
    __shared__ float wred[K2_TPB / 64][E_DIM];
    __shared__ float g1[E_DIM], b1[E_DIM];

    if (tid == 0) {
        float vv[E_DIM];
        #pragma unroll
        for (int e = 0; e < E_DIM; ++e) {
            float v = 0.f;
            #pragma unroll
            for (int i = 0; i < E_DIM; ++i) v += Wv[i * E_DIM + e];
            vv[e] = v;
        }
        for (int h = 0; h < H_N; ++h)
            #pragma unroll
            for (int e = 0; e < E_DIM; ++e)
                Msh[h][e] = vv[2*h] * Wo[(2*h) * E_DIM + e]
                          + vv[2*h+1] * Wo[(2*h+1) * E_DIM + e];
    }
    if (tid < E_DIM) { g1[tid] = ln1_g[tid]; b1[tid] = ln1_b[tid]; }
    __syncthreads();

    float yacc[E_DIM] = {0.f, 0.f, 0.f, 0.f, 0.f, 0.f};
    const float* wb = wls + b * NPAIR;
    for (int s = tid; s < S_LEN; s += K2_TPB) {
        float w0 = wb[s], w1 = wb[S_LEN + s], w2 = wb[2 * S_LEN + s];
        float o[E_DIM];
        float mean = 0.f;
        #pragma unroll
        for (int e = 0; e < E_DIM; ++e) {
            o[e] = w0 * Msh[0][e] + w1 * Msh[1][e] + w2 * Msh[2][e];
            mean += o[e];
        }
        mean *= (1.f / E_DIM);
        float var = 0.f;
        #pragma unroll
        for (int e = 0; e < E_DIM; ++e) { float d = o[e] - mean; var += d * d; }
        var *= (1.f / E_DIM);
        float r = rsqrtf(var + 1e-5f);
        float ln[E_DIM];
        #pragma unroll
        for (int e = 0; e < E_DIM; ++e)
            ln[e] = (o[e] - mean) * r * g1[e] + b1[e];

        const float* wrow = fc1_w + s * E_DIM;
        #pragma unroll
        for (int i = 0; i < E_DIM; ++i) {
            const float* wr = wrow + i * (S_LEN * E_DIM);
            float acc = yacc[i];
            #pragma unroll
            for (int e = 0; e < E_DIM; ++e) acc = fmaf(ln[e], wr[e], acc);
            yacc[i] = acc;
        }
    }

    #pragma unroll
    for (int i = 0; i < E_DIM; ++i)
        for (int off = 32; off > 0; off >>= 1)
            yacc[i] += __shfl_down(yacc[i], off);
    if ((tid & 63) == 0) {
        #pragma unroll
        for (int i = 0; i < E_DIM; ++i) wred[tid >> 6][i] = yacc[i];
    }
    __syncthreads();

    if (tid == 0) {
        const float LOG2E = 1.4426950408889634f;
        float y[E_DIM];
        float mean = 0.f;
        #pragma unroll
        for (int i = 0; i < E_DIM; ++i) {
            float t = wred[0][i];
            for (int w = 1; w < K2_TPB / 64; ++w) t += wred[w][i];
            y[i] = fmaxf(t + fc1_b[i], 0.f);
            mean += y[i];
        }
        mean *= (1.f / E_DIM);
        float var = 0.f;
        #pragma unroll
        for (int i = 0; i < E_DIM; ++i) { float d = y[i] - mean; var += d * d; }
        var *= (1.f / E_DIM);
        float r = rsqrtf(var + 1e-5f);
        float l2[E_DIM];
        #pragma unroll
        for (int i = 0; i < E_DIM; ++i)
            l2[i] = (y[i] - mean) * r * ln2_g[i] + ln2_b[i];

        float z[4];
        float zmax = -1e30f;
        #pragma unroll
        for (int k = 0; k < 4; ++k) {
            float acc = fc2_b[k];
            #pragma unroll
            for (int i = 0; i < E_DIM; ++i)
                acc = fmaf(l2[i], fc2_w[k * E_DIM + i], acc);
            z[k] = acc;
            zmax = fmaxf(zmax, acc);
        }
        float ez[4];
        float se = 0.f;
        #pragma unroll
        for (int k = 0; k < 4; ++k) {
            ez[k] = fast_exp2((z[k] - zmax) * LOG2E);
            se += ez[k];
        }
        float inv = 1.f / se;
        #pragma unroll
        for (int k = 0; k < 4; ++k) out[b * 4 + k] = ez[k] * inv;
    }
}

// ---------------------------------------------------------------------------
// Fallback: single fused kernel (used only if ws_size is too small)
// ---------------------------------------------------------------------------
#define TPB   320
#define NWAVE (TPB / 64)

__global__ __launch_bounds__(TPB, 1) void fused_tx_kernel(
    const float* __restrict__ x,
    const float* __restrict__ Wq, const float* __restrict__ Wk,
    const float* __restrict__ Wv, const float* __restrict__ Wo,
    const float* __restrict__ ln1_g, const float* __restrict__ ln1_b,
    const float* __restrict__ fc1_w, const float* __restrict__ fc1_b,
    const float* __restrict__ ln2_g, const float* __restrict__ ln2_b,
    const float* __restrict__ fc2_w, const float* __restrict__ fc2_b,
    float* __restrict__ out)
{
    const int b   = blockIdx.x;
    const int tid = threadIdx.x;

    __shared__ __align__(16) float xs[S_LEN];
    __shared__ float csh[H_N];
    __shared__ float Msh[H_N][E_DIM];
    __shared__ float wls[H_N][S_LEN];
    __shared__ float wred[NWAVE][2];
    __shared__ float xmax_s, xmin_s;
    __shared__ float ysum[E_DIM];

    for (int i = tid; i < S_LEN; i += TPB) xs[i] = x[b * S_LEN + i];
    if (tid < E_DIM) ysum[tid] = 0.f;

    if (tid == 0) {
        float qv[E_DIM], kv[E_DIM], vv[E_DIM];
        for (int e = 0; e < E_DIM; ++e) {
            float q = 0.f, k = 0.f, v = 0.f;
            for (int i = 0; i < E_DIM; ++i) {
                q += Wq[i * E_DIM + e];
                k += Wk[i * E_DIM + e];
                v += Wv[i * E_DIM + e];
            }
            qv[e] = q; kv[e] = k; vv[e] = v;
        }
        const float inv_sqrt_d = 0.7071067811865476f;
        for (int h = 0; h < H_N; ++h) {
            csh[h] = (qv[2*h] * kv[2*h] + qv[2*h+1] * kv[2*h+1]) * inv_sqrt_d;
            for (int e = 0; e < E_DIM; ++e)
                Msh[h][e] = vv[2*h] * Wo[(2*h) * E_DIM + e]
                          + vv[2*h+1] * Wo[(2*h+1) * E_DIM + e];
        }
    }
    __syncthreads();

    {
        float mx = -1e30f, mn = 1e30f;
        for (int i = tid; i < S_LEN; i += TPB) {
            float v = xs[i];
            mx = fmaxf(mx, v);
            mn = fminf(mn, v);
        }
        for (int off = 32; off > 0; off >>= 1) {
            mx = fmaxf(mx, __shfl_down(mx, off));
            mn = fminf(mn, __shfl_down(mn, off));
        }
        int wave = tid >> 6, lane = tid & 63;
        if (lane == 0) { wred[wave][0] = mx; wred[wave][1] = mn; }
        __syncthreads();
        if (tid == 0) {
            float a = wred[0][0], c = wred[0][1];
            for (int w = 1; w < NWAVE; ++w) {
                a = fmaxf(a, wred[w][0]);
                c = fminf(c, wred[w][1]);
            }
            xmax_s = a; xmin_s = c;
        }
        __syncthreads();
    }

    const float LOG2E = 1.4426950408889634f;
    const float xmax = xmax_s, xmin = xmin_s;
    const float4* xs4 = (const float4*)xs;

    for (int p = tid; p < NPAIR; p += TPB) {
        int h = p / S_LEN;
        int s = p - h * S_LEN;
        float a  = csh[h] * xs[s];
        float a2 = a * LOG2E;
        float m2 = (a >= 0.f ? a * xmax : a * xmin) * LOG2E;

        float den0 = 0.f, den1 = 0.f, den2 = 0.f, den3 = 0.f;
        float num0 = 0.f, num1 = 0.f, num2 = 0.f, num3 = 0.f;
        #pragma unroll 2
        for (int t4 = 0; t4 < S_LEN / 4; ++t4) {
            float4 xv = xs4[t4];
            float e0 = fast_exp2(fmaf(a2, xv.x, -m2));
            float e1 = fast_exp2(fmaf(a2, xv.y, -m2));
            float e2 = fast_exp2(fmaf(a2, xv.z, -m2));
            float e3 = fast_exp2(fmaf(a2, xv.w, -m2));
            den0 += e0; den1 += e1; den2 += e2; den3 += e3;
            num0 = fmaf(e0, xv.x, num0);
            num1 = fmaf(e1, xv.y, num1);
            num2 = fmaf(e2, xv.z, num2);
            num3 = fmaf(e3, xv.w, num3);
        }
        float den = (den0 + den1) + (den2 + den3);
        float num = (num0 + num1) + (num2 + num3);
        wls[h][s] = num / den;
    }
    __syncthreads();

    float yacc[E_DIM] = {0.f, 0.f, 0.f, 0.f, 0.f, 0.f};
    for (int s = tid; s < S_LEN; s += TPB) {
        float w0 = wls[0][s], w1 = wls[1][s], w2 = wls[2][s];
        float o[E_DIM];
        float mean = 0.f;
        #pragma unroll
        for (int e = 0; e < E_DIM; ++e) {
            o[e] = w0 * Msh[0][e] + w1 * Msh[1][e] + w2 * Msh[2][e];
            mean += o[e];
        }
        mean *= (1.f / E_DIM);
        float var = 0.f;
        #pragma unroll
        for (int e = 0; e < E_DIM; ++e) { float d = o[e] - mean; var += d * d; }
        var *= (1.f / E_DIM);
        float r = rsqrtf(var + 1e-5f);
        float ln[E_DIM];
        #pragma unroll
        for (int e = 0; e < E_DIM; ++e)
            ln[e] = (o[e] - mean) * r * ln1_g[e] + ln1_b[e];

        const float* wrow = fc1_w + s * E_DIM;
        #pragma unroll
        for (int i = 0; i < E_DIM; ++i) {
            const float* wr = wrow + i * (S_LEN * E_DIM);
            float acc = yacc[i];
            #pragma unroll
            for (int e = 0; e < E_DIM; ++e) acc = fmaf(ln[e], wr[e], acc);
            yacc[i] = acc;
        }
    }

    #pragma unroll
    for (int i = 0; i < E_DIM; ++i)
        for (int off = 32; off > 0; off >>= 1)
            yacc[i] += __shfl_down(yacc[i], off);
    if ((tid & 63) == 0) {
        #pragma unroll
        for (int i = 0; i < E_DIM; ++i) atomicAdd(&ysum[i], yacc[i]);
    }
    __syncthreads();

    if (tid == 0) {
        float y[E_DIM];
        float mean = 0.f;
        #pragma unroll
        for (int i = 0; i < E_DIM; ++i) {
            y[i] = fmaxf(ysum[i] + fc1_b[i], 0.f);
            mean += y[i];
        }
        mean *= (1.f / E_DIM);
        float var = 0.f;
        #pragma unroll
        for (int i = 0; i < E_DIM; ++i) { float d = y[i] - mean; var += d * d; }
        var *= (1.f / E_DIM);
        float r = rsqrtf(var + 1e-5f);
        float l2[E_DIM];
        #pragma unroll
        for (int i = 0; i < E_DIM; ++i)
            l2[i] = (y[i] - mean) * r * ln2_g[i] + ln2_b[i];

        float z[4];
        float zmax = -1e30f;
        #pragma unroll
        for (int k = 0; k < 4; ++k) {
            float acc = fc2_b[k];
            #pragma unroll
            for (int i = 0; i < E_DIM; ++i)
                acc = fmaf(l2[i], fc2_w[k * E_DIM + i], acc);
            z[k] = acc;
            zmax = fmaxf(zmax, acc);
        }
        float ez[4];
        float se = 0.f;
        #pragma unroll
        for (int k = 0; k < 4; ++k) {
            ez[k] = fast_exp2((z[k] - zmax) * LOG2E);
            se += ez[k];
        }
        float inv = 1.f / se;
        #pragma unroll
        for (int k = 0; k < 4; ++k) out[b * 4 + k] = ez[k] * inv;
    }
}

extern "C" void kernel_launch(void* const* d_in, const int* in_sizes, int n_in,
                              void* d_out, int out_size, void* d_ws, size_t ws_size,
                              hipStream_t stream) {
    const float* x     = (const float*)d_in[0];
    const float* Wq    = (const float*)d_in[1];
    const float* Wk    = (const float*)d_in[2];
    const float* Wv    = (const float*)d_in[3];
    const float* Wo    = (const float*)d_in[4];
    const float* ln1_g = (const float*)d_in[5];
    const float* ln1_b = (const float*)d_in[6];
    const float* fc1_w = (const float*)d_in[7];
    const float* fc1_b = (const float*)d_in[8];
    const float* ln2_g = (const float*)d_in[9];
    const float* ln2_b = (const float*)d_in[10];
    const float* fc2_w = (const float*)d_in[11];
    const float* fc2_b = (const float*)d_in[12];
    float* out = (float*)d_out;

    const int B = in_sizes[0] / S_LEN;   // 256
    const size_t need = (size_t)B * NPAIR * sizeof(float);

    if (ws_size >= need) {
        float* wls = (float*)d_ws;
        dim3 grid1(K1_BLKS, B);
        k1_pairs<<<grid1, K1_TPB, 0, stream>>>(x, Wq, Wk, wls);
        k2_tail<<<B, K2_TPB, 0, stream>>>(wls, Wv, Wo, ln1_g, ln1_b,
                                          fc1_w, fc1_b, ln2_g, ln2_b,
                                          fc2_w, fc2_b, out);
    } else {
        fused_tx_kernel<<<B, TPB, 0, stream>>>(
            x, Wq, Wk, Wv, Wo, ln1_g, ln1_b, fc1_w, fc1_b,
            ln2_g, ln2_b, fc2_w, fc2_b, out);
    }
}

// Round 6
// 38.129 us; speedup vs baseline: 1.2198x; 1.1348x over previous
//
#include <hip/hip_runtime.h>
#include <math.h>

#define S_LEN 520
#define E_DIM 6
#define H_N   3
#define NPAIR (H_N * S_LEN)       // 1560
#define K1_TPB 256
#define K1_BLKS 13                // ceil(2*1560 / 256)
#define K2_TPB 256

typedef float f32x2 __attribute__((ext_vector_type(2)));

__device__ __forceinline__ float fast_exp2(float v) {
#if __has_builtin(__builtin_amdgcn_exp2f)
    return __builtin_amdgcn_exp2f(v);
#else
    return exp2f(v);
#endif
}

__device__ __forceinline__ f32x2 pk_fma(f32x2 a, f32x2 b, f32x2 c) {
    f32x2 d;
    asm("v_pk_fma_f32 %0, %1, %2, %3" : "=v"(d) : "v"(a), "v"(b), "v"(c));
    return d;
}
__device__ __forceinline__ f32x2 pk_add(f32x2 a, f32x2 b) {
    f32x2 d;
    asm("v_pk_add_f32 %0, %1, %2" : "=v"(d) : "v"(a), "v"(b));
    return d;
}

// ---------------------------------------------------------------------------
// K1: TWO threads per (b,h,s) pair — lane 2k sums t in [0,260), lane 2k+1
// sums t in [260,520); combined with one shfl_xor. 13312 waves total
// (~13/SIMD) for latency hiding. One barrier; per-wave stats; LDS float4
// reads + packed fp32 math in the hot loop (proven fastest variant).
// ---------------------------------------------------------------------------
__global__ __launch_bounds__(K1_TPB) void k1_pairs(
    const float* __restrict__ x,
    const float* __restrict__ Wq, const float* __restrict__ Wk,
    float* __restrict__ wls)
{
    const int b   = blockIdx.y;
    const int tid = threadIdx.x;

    __shared__ __align__(16) float xs[S_LEN];

    // stage x row: 130 float4
    if (tid < S_LEN / 4)
        ((float4*)xs)[tid] = ((const float4*)(x + b * S_LEN))[tid];
    __syncthreads();

    // ---- per-wave row max/min from LDS (2-way bank alias = free) ----
    const int lane = tid & 63;
    float mx = -1e30f, mn = 1e30f;
    for (int i = lane; i < S_LEN; i += 64) {
        float v = xs[i];
        mx = fmaxf(mx, v);
        mn = fminf(mn, v);
    }
    #pragma unroll
    for (int off = 32; off > 0; off >>= 1) {
        mx = fmaxf(mx, __shfl_xor(mx, off));
        mn = fminf(mn, __shfl_xor(mn, off));
    }

    // ---- per-wave csh (uniform scalar loads -> s_load; cheap) ----
    float c0, c1, c2;
    {
        const float SC = 0.7071067811865476f * 1.4426950408889634f; // 1/sqrt(2)*log2e
        float cs[H_N];
        #pragma unroll
        for (int h = 0; h < H_N; ++h) {
            float q0 = 0.f, q1 = 0.f, k0 = 0.f, k1 = 0.f;
            #pragma unroll
            for (int i = 0; i < E_DIM; ++i) {
                q0 += Wq[i * E_DIM + 2*h];
                q1 += Wq[i * E_DIM + 2*h + 1];
                k0 += Wk[i * E_DIM + 2*h];
                k1 += Wk[i * E_DIM + 2*h + 1];
            }
            cs[h] = (q0 * k0 + q1 * k1) * SC;
        }
        c0 = cs[0]; c1 = cs[1]; c2 = cs[2];
    }

    const int p2   = blockIdx.x * K1_TPB + tid;
    const int p    = p2 >> 1;          // pair index
    const int half = p2 & 1;           // which 260-element half of t
    if (p >= NPAIR) return;            // both lanes of a pair exit together

    const int h = (p >= 2 * S_LEN) ? 2 : (p >= S_LEN ? 1 : 0);
    const int s = p - h * S_LEN;
    const float c = (h == 0) ? c0 : (h == 1 ? c1 : c2);

    const float a2 = c * xs[s];                         // log2-domain scale
    const float m2 = (a2 >= 0.f) ? a2 * mx : a2 * mn;   // row max of a2*x_t

    const f32x2 a2p  = {a2, a2};
    const f32x2 nm2p = {-m2, -m2};

    const float4* xb4 = (const float4*)xs + half * 65;  // 65 float4 = 260 floats

    f32x2 den0 = {0.f, 0.f}, den1 = {0.f, 0.f}, den2 = {0.f, 0.f}, den3 = {0.f, 0.f};
    f32x2 num0 = {0.f, 0.f}, num1 = {0.f, 0.f}, num2 = {0.f, 0.f}, num3 = {0.f, 0.f};

    for (int it = 0; it < 32; ++it) {
        float4 xa = xb4[2 * it];
        float4 xb = xb4[2 * it + 1];
        f32x2 x0 = {xa.x, xa.y};
        f32x2 x1 = {xa.z, xa.w};
        f32x2 x2 = {xb.x, xb.y};
        f32x2 x3 = {xb.z, xb.w};

        f32x2 g0 = pk_fma(a2p, x0, nm2p);
        f32x2 g1 = pk_fma(a2p, x1, nm2p);
        f32x2 g2 = pk_fma(a2p, x2, nm2p);
        f32x2 g3 = pk_fma(a2p, x3, nm2p);

        f32x2 e0 = { fast_exp2(g0.x), fast_exp2(g0.y) };
        f32x2 e1 = { fast_exp2(g1.x), fast_exp2(g1.y) };
        f32x2 e2 = { fast_exp2(g2.x), fast_exp2(g2.y) };
        f32x2 e3 = { fast_exp2(g3.x), fast_exp2(g3.y) };

        den0 = pk_add(den0, e0);
        den1 = pk_add(den1, e1);
        den2 = pk_add(den2, e2);
        den3 = pk_add(den3, e3);

        num0 = pk_fma(e0, x0, num0);
        num1 = pk_fma(e1, x1, num1);
        num2 = pk_fma(e2, x2, num2);
        num3 = pk_fma(e3, x3, num3);
    }
    {   // tail: 4 elements (260 = 32*8 + 4)
        float4 xa = xb4[64];
        f32x2 x0 = {xa.x, xa.y};
        f32x2 x1 = {xa.z, xa.w};
        f32x2 g0 = pk_fma(a2p, x0, nm2p);
        f32x2 g1 = pk_fma(a2p, x1, nm2p);
        f32x2 e0 = { fast_exp2(g0.x), fast_exp2(g0.y) };
        f32x2 e1 = { fast_exp2(g1.x), fast_exp2(g1.y) };
        den0 = pk_add(den0, e0);
        den1 = pk_add(den1, e1);
        num0 = pk_fma(e0, x0, num0);
        num1 = pk_fma(e1, x1, num1);
    }

    f32x2 denp = pk_add(pk_add(den0, den1), pk_add(den2, den3));
    f32x2 nump = pk_add(pk_add(num0, num1), pk_add(num2, num3));
    float den = denp.x + denp.y;
    float num = nump.x + nump.y;

    // combine the two halves of the pair (lanes 2k <-> 2k+1)
    den += __shfl_xor(den, 1);
    num += __shfl_xor(num, 1);

    if (half == 0)
        wls[(b * H_N + h) * S_LEN + s] = num / den;
}

// ---------------------------------------------------------------------------
// K2: per batch row — Wo-combine + LN1 + fc1 + relu + LN2 + fc2 + softmax(4)
// ---------------------------------------------------------------------------
__global__ __launch_bounds__(K2_TPB, 1) void k2_tail(
    const float* __restrict__ wls,
    const float* __restrict__ Wv, const float* __restrict__ Wo,
    const float* __restrict__ ln1_g, const float* __restrict__ ln1_b,
    const float* __restrict__ fc1_w, const float* __restrict__ fc1_b,
    const float* __restrict__ ln2_g, const float* __restrict__ ln2_b,
    const float* __restrict__ fc2_w, const float* __restrict__ fc2_b,
    float* __restrict__ out)
{
    const int b   = blockIdx.x;
    const int tid = threadIdx.x;

    __shared__ float Msh[H_N][E_DIM];
    __shared__ float wred[K2_TPB / 64][E_DIM];
    __shared__ float g1[E_DIM], b1[E_DIM];

    if (tid == 0) {
        float vv[E_DIM];
        #pragma unroll
        for (int e = 0; e < E_DIM; ++e) {
            float v = 0.f;
            #pragma unroll
            for (int i = 0; i < E_DIM; ++i) v += Wv[i * E_DIM + e];
            vv[e] = v;
        }
        for (int h = 0; h < H_N; ++h)
            #pragma unroll
            for (int e = 0; e < E_DIM; ++e)
                Msh[h][e] = vv[2*h] * Wo[(2*h) * E_DIM + e]
                          + vv[2*h+1] * Wo[(2*h+1) * E_DIM + e];
    }
    if (tid < E_DIM) { g1[tid] = ln1_g[tid]; b1[tid] = ln1_b[tid]; }
    __syncthreads();

    float yacc[E_DIM] = {0.f, 0.f, 0.f, 0.f, 0.f, 0.f};
    const float* wb = wls + b * NPAIR;
    for (int s = tid; s < S_LEN; s += K2_TPB) {
        float w0 = wb[s], w1 = wb[S_LEN + s], w2 = wb[2 * S_LEN + s];
        float o[E_DIM];
        float mean = 0.f;
        #pragma unroll
        for (int e = 0; e < E_DIM; ++e) {
            o[e] = w0 * Msh[0][e] + w1 * Msh[1][e] + w2 * Msh[2][e];
            mean += o[e];
        }
        mean *= (1.f / E_DIM);
        float var = 0.f;
        #pragma unroll
        for (int e = 0; e < E_DIM; ++e) { float d = o[e] - mean; var += d * d; }
        var *= (1.f / E_DIM);
        float r = rsqrtf(var + 1e-5f);
        float ln[E_DIM];
        #pragma unroll
        for (int e = 0; e < E_DIM; ++e)
            ln[e] = (o[e] - mean) * r * g1[e] + b1[e];

        const float* wrow = fc1_w + s * E_DIM;
        #pragma unroll
        for (int i = 0; i < E_DIM; ++i) {
            const float* wr = wrow + i * (S_LEN * E_DIM);
            float acc = yacc[i];
            #pragma unroll
            for (int e = 0; e < E_DIM; ++e) acc = fmaf(ln[e], wr[e], acc);
            yacc[i] = acc;
        }
    }

    #pragma unroll
    for (int i = 0; i < E_DIM; ++i)
        for (int off = 32; off > 0; off >>= 1)
            yacc[i] += __shfl_down(yacc[i], off);
    if ((tid & 63) == 0) {
        #pragma unroll
        for (int i = 0; i < E_DIM; ++i) wred[tid >> 6][i] = yacc[i];
    }
    __syncthreads();

    if (tid == 0) {
        const float LOG2E = 1.4426950408889634f;
        float y[E_DIM];
        float mean = 0.f;
        #pragma unroll
        for (int i = 0; i < E_DIM; ++i) {
            float t = wred[0][i];
            for (int w = 1; w < K2_TPB / 64; ++w) t += wred[w][i];
            y[i] = fmaxf(t + fc1_b[i], 0.f);
            mean += y[i];
        }
        mean *= (1.f / E_DIM);
        float var = 0.f;
        #pragma unroll
        for (int i = 0; i < E_DIM; ++i) { float d = y[i] - mean; var += d * d; }
        var *= (1.f / E_DIM);
        float r = rsqrtf(var + 1e-5f);
        float l2[E_DIM];
        #pragma unroll
        for (int i = 0; i < E_DIM; ++i)
            l2[i] = (y[i] - mean) * r * ln2_g[i] + ln2_b[i];

        float z[4];
        float zmax = -1e30f;
        #pragma unroll
        for (int k = 0; k < 4; ++k) {
            float acc = fc2_b[k];
            #pragma unroll
            for (int i = 0; i < E_DIM; ++i)
                acc = fmaf(l2[i], fc2_w[k * E_DIM + i], acc);
            z[k] = acc;
            zmax = fmaxf(zmax, acc);
        }
        float ez[4];
        float se = 0.f;
        #pragma unroll
        for (int k = 0; k < 4; ++k) {
            ez[k] = fast_exp2((z[k] - zmax) * LOG2E);
            se += ez[k];
        }
        float inv = 1.f / se;
        #pragma unroll
        for (int k = 0; k < 4; ++k) out[b * 4 + k] = ez[k] * inv;
    }
}

// ---------------------------------------------------------------------------
// Fallback: single fused kernel (used only if ws_size is too small)
// ---------------------------------------------------------------------------
#define TPB   320
#define NWAVE (TPB / 64)

__global__ __launch_bounds__(TPB, 1) void fused_tx_kernel(
    const float* __restrict__ x,
    const float* __restrict__ Wq, const float* __restrict__ Wk,
    const float* __restrict__ Wv, const float* __restrict__ Wo,
    const float* __restrict__ ln1_g, const float* __restrict__ ln1_b,
    const float* __restrict__ fc1_w, const float* __restrict__ fc1_b,
    const float* __restrict__ ln2_g, const float* __restrict__ ln2_b,
    const float* __restrict__ fc2_w, const float* __restrict__ fc2_b,
    float* __restrict__ out)
{
    const int b   = blockIdx.x;
    const int tid = threadIdx.x;

    __shared__ __align__(16) float xs[S_LEN];
    __shared__ float csh[H_N];
    __shared__ float Msh[H_N][E_DIM];
    __shared__ float wls[H_N][S_LEN];
    __shared__ float wred[NWAVE][2];
    __shared__ float xmax_s, xmin_s;
    __shared__ float ysum[E_DIM];

    for (int i = tid; i < S_LEN; i += TPB) xs[i] = x[b * S_LEN + i];
    if (tid < E_DIM) ysum[tid] = 0.f;

    if (tid == 0) {
        float qv[E_DIM], kv[E_DIM], vv[E_DIM];
        for (int e = 0; e < E_DIM; ++e) {
            float q = 0.f, k = 0.f, v = 0.f;
            for (int i = 0; i < E_DIM; ++i) {
                q += Wq[i * E_DIM + e];
                k += Wk[i * E_DIM + e];
                v += Wv[i * E_DIM + e];
            }
            qv[e] = q; kv[e] = k; vv[e] = v;
        }
        const float inv_sqrt_d = 0.7071067811865476f;
        for (int h = 0; h < H_N; ++h) {
            csh[h] = (qv[2*h] * kv[2*h] + qv[2*h+1] * kv[2*h+1]) * inv_sqrt_d;
            for (int e = 0; e < E_DIM; ++e)
                Msh[h][e] = vv[2*h] * Wo[(2*h) * E_DIM + e]
                          + vv[2*h+1] * Wo[(2*h+1) * E_DIM + e];
        }
    }
    __syncthreads();

    {
        float mx = -1e30f, mn = 1e30f;
        for (int i = tid; i < S_LEN; i += TPB) {
            float v = xs[i];
            mx = fmaxf(mx, v);
            mn = fminf(mn, v);
        }
        for (int off = 32; off > 0; off >>= 1) {
            mx = fmaxf(mx, __shfl_down(mx, off));
            mn = fminf(mn, __shfl_down(mn, off));
        }
        int wave = tid >> 6, lane = tid & 63;
        if (lane == 0) { wred[wave][0] = mx; wred[wave][1] = mn; }
        __syncthreads();
        if (tid == 0) {
            float a = wred[0][0], c = wred[0][1];
            for (int w = 1; w < NWAVE; ++w) {
                a = fmaxf(a, wred[w][0]);
                c = fminf(c, wred[w][1]);
            }
            xmax_s = a; xmin_s = c;
        }
        __syncthreads();
    }

    const float LOG2E = 1.4426950408889634f;
    const float xmax = xmax_s, xmin = xmin_s;
    const float4* xs4 = (const float4*)xs;

    for (int p = tid; p < NPAIR; p += TPB) {
        int h = p / S_LEN;
        int s = p - h * S_LEN;
        float a  = csh[h] * xs[s];
        float a2 = a * LOG2E;
        float m2 = (a >= 0.f ? a * xmax : a * xmin) * LOG2E;

        float den0 = 0.f, den1 = 0.f, den2 = 0.f, den3 = 0.f;
        float num0 = 0.f, num1 = 0.f, num2 = 0.f, num3 = 0.f;
        #pragma unroll 2
        for (int t4 = 0; t4 < S_LEN / 4; ++t4) {
            float4 xv = xs4[t4];
            float e0 = fast_exp2(fmaf(a2, xv.x, -m2));
            float e1 = fast_exp2(fmaf(a2, xv.y, -m2));
            float e2 = fast_exp2(fmaf(a2, xv.z, -m2));
            float e3 = fast_exp2(fmaf(a2, xv.w, -m2));
            den0 += e0; den1 += e1; den2 += e2; den3 += e3;
            num0 = fmaf(e0, xv.x, num0);
            num1 = fmaf(e1, xv.y, num1);
            num2 = fmaf(e2, xv.z, num2);
            num3 = fmaf(e3, xv.w, num3);
        }
        float den = (den0 + den1) + (den2 + den3);
        float num = (num0 + num1) + (num2 + num3);
        wls[h][s] = num / den;
    }
    __syncthreads();

    float yacc[E_DIM] = {0.f, 0.f, 0.f, 0.f, 0.f, 0.f};
    for (int s = tid; s < S_LEN; s += TPB) {
        float w0 = wls[0][s], w1 = wls[1][s], w2 = wls[2][s];
        float o[E_DIM];
        float mean = 0.f;
        #pragma unroll
        for (int e = 0; e < E_DIM; ++e) {
            o[e] = w0 * Msh[0][e] + w1 * Msh[1][e] + w2 * Msh[2][e];
            mean += o[e];
        }
        mean *= (1.f / E_DIM);
        float var = 0.f;
        #pragma unroll
        for (int e = 0; e < E_DIM; ++e) { float d = o[e] - mean; var += d * d; }
        var *= (1.f / E_DIM);
        float r = rsqrtf(var + 1e-5f);
        float ln[E_DIM];
        #pragma unroll
        for (int e = 0; e < E_DIM; ++e)
            ln[e] = (o[e] - mean) * r * ln1_g[e] + ln1_b[e];

        const float* wrow = fc1_w + s * E_DIM;
        #pragma unroll
        for (int i = 0; i < E_DIM; ++i) {
            const float* wr = wrow + i * (S_LEN * E_DIM);
            float acc = yacc[i];
            #pragma unroll
            for (int e = 0; e < E_DIM; ++e) acc = fmaf(ln[e], wr[e], acc);
            yacc[i] = acc;
        }
    }

    #pragma unroll
    for (int i = 0; i < E_DIM; ++i)
        for (int off = 32; off > 0; off >>= 1)
            yacc[i] += __shfl_down(yacc[i], off);
    if ((tid & 63) == 0) {
        #pragma unroll
        for (int i = 0; i < E_DIM; ++i) atomicAdd(&ysum[i], yacc[i]);
    }
    __syncthreads();

    if (tid == 0) {
        float y[E_DIM];
        float mean = 0.f;
        #pragma unroll
        for (int i = 0; i < E_DIM; ++i) {
            y[i] = fmaxf(ysum[i] + fc1_b[i], 0.f);
            mean += y[i];
        }
        mean *= (1.f / E_DIM);
        float var = 0.f;
        #pragma unroll
        for (int i = 0; i < E_DIM; ++i) { float d = y[i] - mean; var += d * d; }
        var *= (1.f / E_DIM);
        float r = rsqrtf(var + 1e-5f);
        float l2[E_DIM];
        #pragma unroll
        for (int i = 0; i < E_DIM; ++i)
            l2[i] = (y[i] - mean) * r * ln2_g[i] + ln2_b[i];

        float z[4];
        float zmax = -1e30f;
        #pragma unroll
        for (int k = 0; k < 4; ++k) {
            float acc = fc2_b[k];
            #pragma unroll
            for (int i = 0; i < E_DIM; ++i)
                acc = fmaf(l2[i], fc2_w[k * E_DIM + i], acc);
            z[k] = acc;
            zmax = fmaxf(zmax, acc);
        }
        float ez[4];
        float se = 0.f;
        #pragma unroll
        for (int k = 0; k < 4; ++k) {
            ez[k] = fast_exp2((z[k] - zmax) * LOG2E);
            se += ez[k];
        }
        float inv = 1.f / se;
        #pragma unroll
        for (int k = 0; k < 4; ++k) out[b * 4 + k] = ez[k] * inv;
    }
}

extern "C" void kernel_launch(void* const* d_in, const int* in_sizes, int n_in,
                              void* d_out, int out_size, void* d_ws, size_t ws_size,
                              hipStream_t stream) {
    const float* x     = (const float*)d_in[0];
    const float* Wq    = (const float*)d_in[1];
    const float* Wk    = (const float*)d_in[2];
    const float* Wv    = (const float*)d_in[3];
    const float* Wo    = (const float*)d_in[4];
    const float* ln1_g = (const float*)d_in[5];
    const float* ln1_b = (const float*)d_in[6];
    const float* fc1_w = (const float*)d_in[7];
    const float* fc1_b = (const float*)d_in[8];
    const float* ln2_g = (const float*)d_in[9];
    const float* ln2_b = (const float*)d_in[10];
    const float* fc2_w = (const float*)d_in[11];
    const float* fc2_b = (const float*)d_in[12];
    float* out = (float*)d_out;

    const int B = in_sizes[0] / S_LEN;   // 256
    const size_t need = (size_t)B * NPAIR * sizeof(float);

    if (ws_size >= need) {
        float* wls = (float*)d_ws;
        dim3 grid1(K1_BLKS, B);
        k1_pairs<<<grid1, K1_TPB, 0, stream>>>(x, Wq, Wk, wls);
        k2_tail<<<B, K2_TPB, 0, stream>>>(wls, Wv, Wo, ln1_g, ln1_b,
                                          fc1_w, fc1_b, ln2_g, ln2_b,
                                          fc2_w, fc2_b, out);
    } else {
        fused_tx_kernel<<<B, TPB, 0, stream>>>(
            x, Wq, Wk, Wv, Wo, ln1_g, ln1_b, fc1_w, fc1_b,
            ln2_g, ln2_b, fc2_w, fc2_b, out);
    }
}